// Round 2
// baseline (6211.518 us; speedup 1.0000x reference)
//
#include <hip/hip_runtime.h>
#include <hip/hip_bf16.h>

typedef __attribute__((ext_vector_type(8))) short bf16x8;
typedef __attribute__((ext_vector_type(4))) float f32x4;

__device__ inline unsigned short f2b(float x){
  union { float f; unsigned int u; } v; v.f = x;
  unsigned int u = v.u;
  return (unsigned short)((u + 0x7FFFu + ((u >> 16) & 1u)) >> 16);
}
__device__ inline float b2f(unsigned short h){
  union { unsigned int u; float f; } v; v.u = ((unsigned int)h) << 16; return v.f;
}

__global__ __launch_bounds__(256) void zerofill(float* __restrict__ p, int n){
  int i = blockIdx.x * 256 + threadIdx.x;
  if (i < n) p[i] = 0.f;
}

// ---------------- prep: W_sum = W_ih + W_hh (bf16), W_hh bf16, bias_sum ----------------
__global__ __launch_bounds__(256) void prep_w(
    const float* __restrict__ Wih, const float* __restrict__ Whh,
    const float* __restrict__ bih, const float* __restrict__ bhh,
    unsigned short* __restrict__ Wsum, unsigned short* __restrict__ Whhb,
    float* __restrict__ bias_sum)
{
  size_t idx = (size_t)blockIdx.x * 256 + threadIdx.x; // 4096*1024
  float wi = Wih[idx], wh = Whh[idx];
  Wsum[idx] = f2b(wi + wh);
  Whhb[idx] = f2b(wh);
  if (idx < 4096) bias_sum[idx] = bih[idx] + bhh[idx];
}

// bias0[n] = bias_sum[n] + sum_k W_ih[n,k]*go[0,k]   (go batch-uniform in reference)
__global__ __launch_bounds__(256) void prep_b0(
    const float* __restrict__ Wih, const float* __restrict__ go,
    const float* __restrict__ bias_sum, float* __restrict__ bias0)
{
  __shared__ float red[4];
  int n = blockIdx.x, t = threadIdx.x;
  float acc = 0.f;
  for (int k = t; k < 1024; k += 256) acc += Wih[(size_t)n*1024 + k] * go[k];
  for (int off = 32; off > 0; off >>= 1) acc += __shfl_down(acc, off, 64);
  if ((t & 63) == 0) red[t >> 6] = acc;
  __syncthreads();
  if (t == 0) bias0[n] = bias_sum[n] + red[0] + red[1] + red[2] + red[3];
}

// ---------------- z projections (K=128, f32) ----------------
__global__ __launch_bounds__(256) void zproj(
    const float* __restrict__ z, const float* __restrict__ Wzh, const float* __restrict__ bzh,
    const float* __restrict__ Wzc, const float* __restrict__ bzc,
    float* __restrict__ zh_raw, float* __restrict__ zc_raw)
{
  int idx = blockIdx.x * 256 + threadIdx.x; // 256*1024
  int b = idx >> 10, c = idx & 1023;
  const float* zr = z + b * 128;
  const float* wh = Wzh + c * 128;
  const float* wc = Wzc + c * 128;
  float s1 = bzh[c], s2 = bzc[c];
  #pragma unroll 8
  for (int k = 0; k < 128; k++){ float zv = zr[k]; s1 += zv * wh[k]; s2 += zv * wc[k]; }
  zh_raw[idx] = s1; zc_raw[idx] = s2;
}

// ---------------- BN over batch (256 rows) for zh -> h_b (bf16), zc -> c_f ----------------
__global__ __launch_bounds__(256) void bn_init(
    const float* __restrict__ zh_raw, const float* __restrict__ zc_raw,
    const float* __restrict__ g_h, const float* __restrict__ bt_h,
    const float* __restrict__ g_c, const float* __restrict__ bt_c,
    unsigned short* __restrict__ h_b, float* __restrict__ c_f)
{
  __shared__ float red[4][4];
  int c = blockIdx.x, r = threadIdx.x;
  float v1 = zh_raw[r * 1024 + c];
  float v2 = zc_raw[r * 1024 + c];
  float s[4] = { v1, v1*v1, v2, v2*v2 };
  #pragma unroll
  for (int i = 0; i < 4; i++){
    float x = s[i];
    for (int off = 32; off > 0; off >>= 1) x += __shfl_down(x, off, 64);
    if ((r & 63) == 0) red[i][r >> 6] = x;
  }
  __syncthreads();
  float m1 = (red[0][0]+red[0][1]+red[0][2]+red[0][3]) * (1.f/256.f);
  float q1 = (red[1][0]+red[1][1]+red[1][2]+red[1][3]) * (1.f/256.f);
  float m2 = (red[2][0]+red[2][1]+red[2][2]+red[2][3]) * (1.f/256.f);
  float q2 = (red[3][0]+red[3][1]+red[3][2]+red[3][3]) * (1.f/256.f);
  float var1 = q1 - m1*m1; if (var1 < 0.f) var1 = 0.f;
  float var2 = q2 - m2*m2; if (var2 < 0.f) var2 = 0.f;
  float a1 = g_h[c] * rsqrtf(var1 + 1e-5f), be1 = bt_h[c] - m1*a1;
  float a2 = g_c[c] * rsqrtf(var2 + 1e-5f), be2 = bt_c[c] - m2*a2;
  h_b[r * 1024 + c] = f2b(v1*a1 + be1);
  c_f[r * 1024 + c] = v2*a2 + be2;
}

// ---------------- generic bf16 GEMM: out[M][N] = A[M][K] @ B[N][K]^T + bias ----------------
// grid: (N/64, M/64); block 256 (4 waves as 2x2 of 32x32 sub-tiles)
template<int K, int ACT, int OBF16>
__global__ __launch_bounds__(256) void gemm_bt(
    const unsigned short* __restrict__ A, const unsigned short* __restrict__ B,
    const float* __restrict__ bias, void* __restrict__ outp, int N)
{
  const int tid = threadIdx.x;
  const int w = tid >> 6, l = tid & 63;
  const int lr = l & 15, lg = l >> 4;
  const int m0 = blockIdx.y * 64 + (w >> 1) * 32;
  const int n0 = blockIdx.x * 64 + (w & 1) * 32;
  f32x4 acc[2][2];
  #pragma unroll
  for (int i = 0; i < 2; i++)
    #pragma unroll
    for (int j = 0; j < 2; j++) acc[i][j] = (f32x4){0.f,0.f,0.f,0.f};

  const unsigned short* pa0 = A + (size_t)(m0 + lr) * K + lg * 8;
  const unsigned short* pa1 = pa0 + (size_t)16 * K;
  const unsigned short* pb0 = B + (size_t)(n0 + lr) * K + lg * 8;
  const unsigned short* pb1 = pb0 + (size_t)16 * K;

  for (int kb = 0; kb < K; kb += 32){
    bf16x8 a0 = *(const bf16x8*)(pa0 + kb);
    bf16x8 a1 = *(const bf16x8*)(pa1 + kb);
    bf16x8 b0 = *(const bf16x8*)(pb0 + kb);
    bf16x8 b1 = *(const bf16x8*)(pb1 + kb);
    acc[0][0] = __builtin_amdgcn_mfma_f32_16x16x32_bf16(a0, b0, acc[0][0], 0, 0, 0);
    acc[0][1] = __builtin_amdgcn_mfma_f32_16x16x32_bf16(a0, b1, acc[0][1], 0, 0, 0);
    acc[1][0] = __builtin_amdgcn_mfma_f32_16x16x32_bf16(a1, b0, acc[1][0], 0, 0, 0);
    acc[1][1] = __builtin_amdgcn_mfma_f32_16x16x32_bf16(a1, b1, acc[1][1], 0, 0, 0);
  }

  #pragma unroll
  for (int mi = 0; mi < 2; mi++)
    #pragma unroll
    for (int ni = 0; ni < 2; ni++){
      int col = n0 + ni * 16 + lr;
      float bs = bias[col];
      #pragma unroll
      for (int j = 0; j < 4; j++){
        int row = m0 + mi * 16 + lg * 4 + j;
        float v = acc[mi][ni][j] + bs;
        if (ACT) v = v > 0.f ? v : 0.01f * v;
        if (OBF16) ((unsigned short*)outp)[(size_t)row * N + col] = f2b(v);
        else       ((float*)outp)[(size_t)row * N + col] = v;
      }
    }
}

// ---------------- LSTM cell elementwise ----------------
__global__ __launch_bounds__(256) void lstm_cell(
    const float* __restrict__ gates, float* __restrict__ c,
    unsigned short* __restrict__ h_b, unsigned short* __restrict__ hstage_t)
{
  int idx = blockIdx.x * 256 + threadIdx.x; // 256*1024
  int b = idx >> 10, h = idx & 1023;
  const float* g = gates + (size_t)b * 4096;
  float ig = g[h], fg = g[1024 + h], gg = g[2048 + h], og = g[3072 + h];
  float co = c[idx];
  float si = 1.f / (1.f + expf(-ig));
  float sf = 1.f / (1.f + expf(-fg));
  float so = 1.f / (1.f + expf(-og));
  float c2 = sf * co + si * tanhf(gg);
  float h2 = so * tanhf(c2);
  c[idx] = c2;
  unsigned short hb = f2b(h2);
  h_b[idx] = hb;
  hstage_t[idx] = hb;
}

// ---------------- chunk transpose: hstage [32][262144] -> ys [262144][256] cols t0..t0+31 ----
__global__ __launch_bounds__(256) void chunk_tr(
    const unsigned short* __restrict__ in, unsigned short* __restrict__ out, int t0)
{
  __shared__ unsigned short tile[32][66];
  int bh0 = blockIdx.x * 64;
  int tx = threadIdx.x & 63, ty = threadIdx.x >> 6; // ty 0..3
  #pragma unroll
  for (int i = 0; i < 8; i++){
    int tt = ty + i * 4; // 0..31
    tile[tt][tx] = in[(size_t)tt * 262144 + bh0 + tx];
  }
  __syncthreads();
  int tl = threadIdx.x & 31, rr = threadIdx.x >> 5; // rr 0..7
  #pragma unroll
  for (int i = 0; i < 8; i++){
    int xx = rr + i * 8; // 0..63
    out[(size_t)(bh0 + xx) * 256 + t0 + tl] = tile[tl][xx];
  }
}

// ---------------- column stats (sum, sumsq), stage 1 ----------------
template<int C>
__global__ __launch_bounds__(256) void stats1(
    const unsigned short* __restrict__ X, float* __restrict__ psum, float* __restrict__ psq)
{
  int col = blockIdx.x * 256 + threadIdx.x;
  int r0 = blockIdx.y * 256;
  float s = 0.f, q = 0.f;
  for (int r = r0; r < r0 + 256; r++){
    float v = b2f(X[(size_t)r * C + col]);
    s += v; q += v * v;
  }
  psum[(size_t)blockIdx.y * C + col] = s;
  psq [(size_t)blockIdx.y * C + col] = q;
}

__global__ __launch_bounds__(256) void stats2(
    const float* __restrict__ psum, const float* __restrict__ psq,
    const float* __restrict__ g, const float* __restrict__ b,
    float* __restrict__ alpha, float* __restrict__ beta, int C)
{
  int c = blockIdx.x * 256 + threadIdx.x;
  if (c >= C) return;
  float s = 0.f, q = 0.f;
  for (int i = 0; i < 256; i++){ s += psum[(size_t)i * C + c]; q += psq[(size_t)i * C + c]; }
  float m = s * (1.f / 65536.f);
  float var = q * (1.f / 65536.f) - m * m; if (var < 0.f) var = 0.f;
  float a = g[c] * rsqrtf(var + 1e-5f);
  alpha[c] = a; beta[c] = b[c] - m * a;
}

// ---------------- fold BN into weights: Wb = bf16(W*alpha), bp = bias + W.beta ----------------
template<int K>
__global__ __launch_bounds__(256) void foldk(
    const float* __restrict__ W, const float* __restrict__ bias,
    const float* __restrict__ alpha, const float* __restrict__ beta,
    unsigned short* __restrict__ Wb, float* __restrict__ bp, int rows)
{
  __shared__ float red[4];
  int o = blockIdx.x, t = threadIdx.x;
  float acc = 0.f;
  if (o < rows){
    for (int j = t; j < K; j += 256){
      float wv = W[(size_t)o * K + j];
      acc += beta[j] * wv;
      Wb[(size_t)o * K + j] = f2b(wv * alpha[j]);
    }
  } else {
    for (int j = t; j < K; j += 256) Wb[(size_t)o * K + j] = 0;
  }
  for (int off = 32; off > 0; off >>= 1) acc += __shfl_down(acc, off, 64);
  if ((t & 63) == 0) red[t >> 6] = acc;
  __syncthreads();
  if (t == 0) bp[o] = (o < rows ? bias[o] : 0.f) + red[0] + red[1] + red[2] + red[3];
}

// ---------------- final softmax with raw-reshape index mixing ----------------
// o3p: [65536][128] bf16 (valid cols 0..99). out[b,u,v] = softmax_u over tile[u*256+v]
__global__ __launch_bounds__(256) void softmax_k(
    const unsigned short* __restrict__ o3p, float* __restrict__ out)
{
  __shared__ unsigned short tile[25600];
  int b = blockIdx.x, t = threadIdx.x;
  const unsigned short* src = o3p + (size_t)b * 256 * 128;
  for (int i = t; i < 25600; i += 256){
    int rr = i / 100, nc = i - rr * 100;
    tile[i] = src[rr * 128 + nc];
  }
  __syncthreads();
  int v = t;
  float mx = -1e30f;
  for (int u = 0; u < 100; u++) mx = fmaxf(mx, b2f(tile[u * 256 + v]));
  float s = 0.f;
  for (int u = 0; u < 100; u++) s += expf(b2f(tile[u * 256 + v]) - mx);
  float inv = 1.f / s;
  float* dst = out + (size_t)b * 25600;
  for (int u = 0; u < 100; u++)
    dst[u * 256 + v] = expf(b2f(tile[u * 256 + v]) - mx) * inv;
}

extern "C" void kernel_launch(void* const* d_in, const int* in_sizes, int n_in,
                              void* d_out, int out_size, void* d_ws, size_t ws_size,
                              hipStream_t stream)
{
  (void)in_sizes; (void)n_in;
  const float* z     = (const float*)d_in[0];
  const float* Wzh   = (const float*)d_in[1];
  const float* bzh   = (const float*)d_in[2];
  const float* Wzc   = (const float*)d_in[3];
  const float* bzc   = (const float*)d_in[4];
  const float* g_bnzh= (const float*)d_in[5];
  const float* b_bnzh= (const float*)d_in[6];
  const float* g_bnzc= (const float*)d_in[7];
  const float* b_bnzc= (const float*)d_in[8];
  const float* Wih   = (const float*)d_in[9];
  const float* bih   = (const float*)d_in[10];
  const float* Whh   = (const float*)d_in[11];
  const float* bhh   = (const float*)d_in[12];
  const float* g_bn0 = (const float*)d_in[13];
  const float* b_bn0 = (const float*)d_in[14];
  const float* W1    = (const float*)d_in[15];
  const float* b1    = (const float*)d_in[16];
  const float* g_bn1 = (const float*)d_in[17];
  const float* b_bn1 = (const float*)d_in[18];
  const float* W2    = (const float*)d_in[19];
  const float* b2    = (const float*)d_in[20];
  const float* g_bn2 = (const float*)d_in[21];
  const float* b_bn2 = (const float*)d_in[22];
  const float* W3    = (const float*)d_in[23];
  const float* b3    = (const float*)d_in[24];
  const float* go    = (const float*)d_in[25];

  char* base = (char*)d_ws;
  size_t off = 0;
  auto alloc = [&](size_t bytes)->char*{
    char* p = base + off;
    off = (off + bytes + 255) & ~(size_t)255;
    return p;
  };
  const size_t MB = 1024 * 1024;
  // --- reuse zone (dead after LSTM; o2 overlays it) ---
  unsigned short* Wsum   = (unsigned short*)alloc(8 * MB);
  unsigned short* Whhb   = (unsigned short*)alloc(8 * MB);
  float*          gates  = (float*)alloc(4 * MB);
  unsigned short* hstage = (unsigned short*)alloc(16 * MB);   // 32 steps x 262144 bf16
  float*          zh_raw = (float*)alloc(1 * MB);
  float*          zc_raw = (float*)alloc(1 * MB);
  // --- persistent small ---
  float* bias_s = (float*)alloc(16384);
  float* bias0  = (float*)alloc(16384);
  unsigned short* h_b = (unsigned short*)alloc((size_t)256 * 1024 * 2);
  float* c_f    = (float*)alloc((size_t)256 * 1024 * 4);
  float* psum   = (float*)alloc(1 * MB);
  float* psq    = (float*)alloc(1 * MB);
  float* alpha0 = (float*)alloc(4096); float* beta0 = (float*)alloc(4096);
  float* alpha1 = (float*)alloc(4096); float* beta1 = (float*)alloc(4096);
  float* alpha2 = (float*)alloc(4096); float* beta2 = (float*)alloc(4096);
  unsigned short* W1b = (unsigned short*)alloc((size_t)512 * 1024 * 2);
  unsigned short* W2b = (unsigned short*)alloc((size_t)256 * 512 * 2);
  unsigned short* W3b = (unsigned short*)alloc((size_t)128 * 256 * 2);
  float* b1p = (float*)alloc(4096);
  float* b2p = (float*)alloc(4096);
  float* b3p = (float*)alloc(4096);
  // --- big ---
  unsigned short* ys = (unsigned short*)alloc((size_t)262144 * 256 * 2); // 128 MB, [B*H][T] == [65536][1024] flat
  unsigned short* o1 = (unsigned short*)alloc((size_t)65536 * 512 * 2);  // 64 MB
  unsigned short* o2  = (unsigned short*)base;  // 32 MB, overlays reuse zone (dead)
  unsigned short* o3p = ys;                     // 16 MB, overlays ys (dead after gemm1)

  if (off > ws_size){
    // diagnostic clean-fail: workspace too small
    zerofill<<<(out_size + 255) / 256, 256, 0, stream>>>((float*)d_out, out_size);
    return;
  }

  prep_w<<<16384, 256, 0, stream>>>(Wih, Whh, bih, bhh, Wsum, Whhb, bias_s);
  prep_b0<<<4096, 256, 0, stream>>>(Wih, go, bias_s, bias0);
  zproj<<<1024, 256, 0, stream>>>(z, Wzh, bzh, Wzc, bzc, zh_raw, zc_raw);
  bn_init<<<1024, 256, 0, stream>>>(zh_raw, zc_raw, g_bnzh, b_bnzh, g_bnzc, b_bnzc, h_b, c_f);

  for (int t = 0; t < 256; t++){
    const unsigned short* Wb = (t == 0) ? Whhb : Wsum;
    const float* bs = (t == 0) ? bias0 : bias_s;
    gemm_bt<1024, 0, 0><<<dim3(64, 4), 256, 0, stream>>>(h_b, Wb, bs, gates, 4096);
    lstm_cell<<<1024, 256, 0, stream>>>(gates, c_f, h_b,
                                        hstage + (size_t)(t & 31) * 262144);
    if ((t & 31) == 31)
      chunk_tr<<<4096, 256, 0, stream>>>(hstage, ys, t - 31);
  }

  stats1<1024><<<dim3(4, 256), 256, 0, stream>>>(ys, psum, psq);
  stats2<<<4, 256, 0, stream>>>(psum, psq, g_bn0, b_bn0, alpha0, beta0, 1024);
  foldk<1024><<<512, 256, 0, stream>>>(W1, b1, alpha0, beta0, W1b, b1p, 512);
  gemm_bt<1024, 1, 1><<<dim3(8, 1024), 256, 0, stream>>>(ys, W1b, b1p, o1, 512);

  stats1<512><<<dim3(2, 256), 256, 0, stream>>>(o1, psum, psq);
  stats2<<<2, 256, 0, stream>>>(psum, psq, g_bn1, b_bn1, alpha1, beta1, 512);
  foldk<512><<<256, 256, 0, stream>>>(W2, b2, alpha1, beta1, W2b, b2p, 256);
  gemm_bt<512, 1, 1><<<dim3(4, 1024), 256, 0, stream>>>(o1, W2b, b2p, o2, 256);

  stats1<256><<<dim3(1, 256), 256, 0, stream>>>(o2, psum, psq);
  stats2<<<1, 256, 0, stream>>>(psum, psq, g_bn2, b_bn2, alpha2, beta2, 256);
  foldk<256><<<128, 256, 0, stream>>>(W3, b3, alpha2, beta2, W3b, b3p, 100);
  gemm_bt<256, 0, 1><<<dim3(2, 1024), 256, 0, stream>>>(o2, W3b, b3p, o3p, 128);

  softmax_k<<<256, 256, 0, stream>>>(o3p, (float*)d_out);
}